// Round 8
// baseline (395.333 us; speedup 1.0000x reference)
//
#include <hip/hip_runtime.h>
#include <hip/hip_fp16.h>

typedef _Float16 half4v __attribute__((ext_vector_type(4)));
typedef _Float16 half8v __attribute__((ext_vector_type(8)));
typedef float floatx4 __attribute__((ext_vector_type(4)));

#define GLOBAL_AS __attribute__((address_space(1)))
#define LDS_AS __attribute__((address_space(3)))

// async 16B/lane global->LDS DMA; lds dest = wave-uniform base + lane*16
__device__ __forceinline__ void async_copy16(const _Float16* g, _Float16* l) {
    __builtin_amdgcn_global_load_lds((const GLOBAL_AS unsigned int*)g,
                                     (LDS_AS unsigned int*)l, 16, 0, 0);
}

// ---------------- fused preprocessing: converts + 3 transposes, one launch --------
// Also zeroes the PV split-K flags (block 0) -- workspace is re-poisoned between
// harness iterations, so flags must be reset in-stream every launch.
__device__ __forceinline__ void transpose_tile(const float* __restrict__ in,
                                               _Float16* __restrict__ out,
                                               int R, int C, int bx, int by,
                                               float* tile /*[32][33]*/) {
    int tx = threadIdx.x & 31, ty = threadIdx.x >> 5;  // 32x8
    int bc = bx * 32, br = by * 32;
#pragma unroll
    for (int i = 0; i < 32; i += 8)
        tile[(ty + i) * 33 + tx] = in[(size_t)(br + ty + i) * C + bc + tx];
    __syncthreads();
#pragma unroll
    for (int i = 0; i < 32; i += 8)
        out[(size_t)(bc + ty + i) * R + br + tx] = (_Float16)tile[tx * 33 + ty + i];
}

__global__ __launch_bounds__(256) void k_preproc(const float* __restrict__ x,
                                                 _Float16* __restrict__ xh,
                                                 const float* __restrict__ q,
                                                 _Float16* __restrict__ qh,
                                                 const float* __restrict__ Wk,
                                                 _Float16* __restrict__ wkT,
                                                 const float* __restrict__ Wq,
                                                 _Float16* __restrict__ wqT,
                                                 const float* __restrict__ y,
                                                 _Float16* __restrict__ yT,
                                                 int* __restrict__ flags) {
    __shared__ float tile[32 * 33];
    const int b = blockIdx.x;
    if (b == 0 && threadIdx.x < 64) flags[threadIdx.x] = 0;
    if (b < 12288) {
        const int na = 8192 * 1024;
        int i = (b * 256 + threadIdx.x) * 4;
        const float* src;
        _Float16* dst;
        if (i < na) { src = x + i; dst = xh + i; }
        else        { src = q + (i - na); dst = qh + (i - na); }
        float4 v = *(const float4*)src;
        half4v h;
        h[0] = (_Float16)v.x; h[1] = (_Float16)v.y;
        h[2] = (_Float16)v.z; h[3] = (_Float16)v.w;
        *(half4v*)dst = h;
    } else if (b < 12800) {
        const int idx = b - 12288;
        transpose_tile(Wk, wkT, 1024, 512, idx & 15, idx >> 4, tile);
    } else if (b < 13312) {
        const int idx = b - 12800;
        transpose_tile(Wq, wqT, 1024, 512, idx & 15, idx >> 4, tile);
    } else {
        const int idx = b - 13312;
        transpose_tile(y, yT, 8192, 256, idx & 7, idx >> 3, tile);
    }
}

// ---------------- NT GEMM (m97-structure): C = scale * A @ B^T ----------------
// 128x128 tile, BK=64, 4 waves, mfma_f32_16x16x32_f16, global_load_lds width=16,
// chunk-XOR swizzle (bank-conflict-free, proven SQ_LDS_BANK_CONFLICT==0).
// OUT_MODE 0: f16 store (scaled).
// OUT_MODE 1: f32 partial store at C + z*M*N, then split-K last-block-done
//             reduction into Out (device-scope fence + per-tile atomic counter;
//             no spin-wait; z-ascending sum -> bitwise-deterministic).
// OUT_MODE 3: merged projections -- blockIdx.y >= 64 switches to (A2,B2,C2,scale2).
template <int OUT_MODE>
__global__ __launch_bounds__(256) void k_gemm_nt(const _Float16* __restrict__ A,
                                                 const _Float16* __restrict__ B,
                                                 void* __restrict__ C,
                                                 const _Float16* __restrict__ A2,
                                                 const _Float16* __restrict__ B2,
                                                 void* __restrict__ C2,
                                                 float* __restrict__ Out,
                                                 int* __restrict__ flags,
                                                 int M, int N, int K, int kChunk,
                                                 float scale, float scale2) {
    __shared__ __align__(16) _Float16 As[128 * 64];
    __shared__ __align__(16) _Float16 Bs[128 * 64];
    const int tid  = threadIdx.x;
    const int lane = tid & 63;
    const int wave = tid >> 6;
    const int wm   = (wave >> 1) * 64;
    const int wn   = (wave & 1) * 64;
    const int quad = lane >> 4;
    const int lr   = lane & 15;

    int by = blockIdx.y;
    if (OUT_MODE == 3 && by >= 64) {
        by -= 64;
        A = A2; B = B2; C = C2; scale = scale2;
    }
    const long m0 = (long)by * 128;
    const long n0 = (long)blockIdx.x * 128;
    const int kBegin = blockIdx.z * kChunk;
    const int kEnd   = kBegin + kChunk;

    floatx4 acc[4][4] = {};

    const int rl = lane >> 3;
    const int gc = (lane & 7) ^ rl;
    const long arow = m0 + wave * 32 + rl;
    const long brow = n0 + wave * 32 + rl;

    for (int kt = kBegin; kt < kEnd; kt += 64) {
        const _Float16* Ap = A + arow * (long)K + kt + gc * 8;
        const _Float16* Bp = B + brow * (long)K + kt + gc * 8;
        _Float16* Al = &As[(wave * 32) * 64];
        _Float16* Bl = &Bs[(wave * 32) * 64];
#pragma unroll
        for (int i = 0; i < 4; ++i) {
            async_copy16(Ap + (long)(i * 8) * K, Al + i * 8 * 64);
            async_copy16(Bp + (long)(i * 8) * K, Bl + i * 8 * 64);
        }
        __syncthreads();

#pragma unroll
        for (int kk = 0; kk < 64; kk += 32) {
            half8v af[4], bf[4];
            const int cg = (kk >> 3) + quad;
            const int sl = (cg ^ (lr & 7)) * 8;
#pragma unroll
            for (int i = 0; i < 4; ++i)
                af[i] = *(const half8v*)&As[(wm + i * 16 + lr) * 64 + sl];
#pragma unroll
            for (int j = 0; j < 4; ++j)
                bf[j] = *(const half8v*)&Bs[(wn + j * 16 + lr) * 64 + sl];
#pragma unroll
            for (int i = 0; i < 4; ++i)
#pragma unroll
                for (int j = 0; j < 4; ++j)
                    acc[i][j] = __builtin_amdgcn_mfma_f32_16x16x32_f16(af[i], bf[j], acc[i][j], 0, 0, 0);
        }
        __syncthreads();
    }

    // epilogue: C/D layout col = lane&15, row = quad*4 + reg  [m89/m91]
#pragma unroll
    for (int i = 0; i < 4; ++i) {
        long rbase = m0 + wm + i * 16 + quad * 4;
#pragma unroll
        for (int j = 0; j < 4; ++j) {
            long col = n0 + wn + j * 16 + lr;
#pragma unroll
            for (int r = 0; r < 4; ++r) {
                float val = acc[i][j][r] * scale;
                if (OUT_MODE == 1)
                    ((float*)C)[(size_t)blockIdx.z * M * N + (rbase + r) * (long)N + col] = val;
                else
                    ((_Float16*)C)[(rbase + r) * (long)N + col] = (_Float16)val;
            }
        }
    }

    if constexpr (OUT_MODE == 1) {
        // split-K combine: last block for this (x,y) tile sums the 4 partials.
        __threadfence();  // release partial stores to device scope (LLC)
        __shared__ int lastz;
        if (tid == 0)
            lastz = __hip_atomic_fetch_add(&flags[blockIdx.y * gridDim.x + blockIdx.x],
                                           1, __ATOMIC_ACQ_REL, __HIP_MEMORY_SCOPE_AGENT);
        __syncthreads();
        if (lastz == 3) {
            __threadfence();  // acquire: make other blocks' partials visible
            float* part = (float*)C;
            // tile = 128 rows x 128 cols of [M][N=256] f32; 32 float4/row
            for (int it = tid; it < 4096; it += 256) {
                const int rr = it >> 5;
                const int cc = (it & 31) * 4;
                const size_t off = (size_t)(m0 + rr) * N + n0 + cc;
                float4 s = *(const float4*)(part + off);
#pragma unroll
                for (int z = 1; z < 4; ++z) {
                    float4 v = *(const float4*)(part + (size_t)z * M * N + off);
                    s.x += v.x; s.y += v.y; s.z += v.z; s.w += v.w;
                }
                *(float4*)(Out + off) = s;
            }
        }
    }
}

// ---------------- masked softmax, in-place on f16 logits [4096][8192] ----------------
// Coalesced int4 mask + half4 logit loads; moves 268 MB (mask 134 + logits
// r67+w67) at its HBM roofline (~45 us). Mask fusion elsewhere: closed (r1/r4).
__global__ __launch_bounds__(256) void k_softmax(_Float16* __restrict__ logits,
                                                 const int* __restrict__ mask) {
    const int q   = blockIdx.x;
    const int tid = threadIdx.x;
    _Float16* row   = logits + (size_t)q * 8192;
    const int* mrow = mask + (size_t)q * 8192;

    float v[32];
    unsigned mb = 0;
    float lmax = -3.0e38f;
#pragma unroll
    for (int i = 0; i < 8; ++i) {
        int base = i * 1024 + tid * 4;
        int4 mm  = *(const int4*)(mrow + base);
        half4v h = *(const half4v*)(row + base);
#pragma unroll
        for (int j = 0; j < 4; ++j) v[i * 4 + j] = (float)h[j];
        if (mm.x > 0) { mb |= 1u << (i * 4 + 0); lmax = fmaxf(lmax, v[i * 4 + 0]); }
        if (mm.y > 0) { mb |= 1u << (i * 4 + 1); lmax = fmaxf(lmax, v[i * 4 + 1]); }
        if (mm.z > 0) { mb |= 1u << (i * 4 + 2); lmax = fmaxf(lmax, v[i * 4 + 2]); }
        if (mm.w > 0) { mb |= 1u << (i * 4 + 3); lmax = fmaxf(lmax, v[i * 4 + 3]); }
    }
#pragma unroll
    for (int off = 32; off > 0; off >>= 1) lmax = fmaxf(lmax, __shfl_xor(lmax, off, 64));
    __shared__ float redmax[4], redsum[4];
    if ((tid & 63) == 0) redmax[tid >> 6] = lmax;
    __syncthreads();
    lmax = fmaxf(fmaxf(redmax[0], redmax[1]), fmaxf(redmax[2], redmax[3]));

    float lsum = 0.f;
#pragma unroll
    for (int i = 0; i < 32; ++i) {
        float e = ((mb >> i) & 1u) ? __expf(v[i] - lmax) : 0.f;
        v[i] = e;
        lsum += e;
    }
#pragma unroll
    for (int off = 32; off > 0; off >>= 1) lsum += __shfl_xor(lsum, off, 64);
    if ((tid & 63) == 0) redsum[tid >> 6] = lsum;
    __syncthreads();
    lsum = redsum[0] + redsum[1] + redsum[2] + redsum[3];
    float inv = lsum > 0.f ? 1.f / lsum : 0.f;

#pragma unroll
    for (int i = 0; i < 8; ++i) {
        int base = i * 1024 + tid * 4;
        half4v h;
#pragma unroll
        for (int j = 0; j < 4; ++j) h[j] = (_Float16)(v[i * 4 + j] * inv);
        *(half4v*)(row + base) = h;
    }
}

extern "C" void kernel_launch(void* const* d_in, const int* in_sizes, int n_in,
                              void* d_out, int out_size, void* d_ws, size_t ws_size,
                              hipStream_t stream) {
    const float* search_x = (const float*)d_in[0];  // [8192,1024]
    const float* search_y = (const float*)d_in[1];  // [8192,256]
    const float* query_x  = (const float*)d_in[2];  // [4096,1024]
    const int*   mask     = (const int*)d_in[3];    // [4096,8192]
    const float* Wk       = (const float*)d_in[4];  // [1024,512]
    const float* Wq       = (const float*)d_in[5];  // [1024,512]
    (void)in_sizes; (void)n_in; (void)ws_size; (void)out_size;

    char* p = (char*)d_ws;
    _Float16* xh   = (_Float16*)p; p += (size_t)8192 * 1024 * 2;  // x f16
    _Float16* qh   = (_Float16*)p; p += (size_t)4096 * 1024 * 2;  // q f16
    _Float16* wkT  = (_Float16*)p; p += (size_t)512 * 1024 * 2;   // Wk^T f16
    _Float16* wqT  = (_Float16*)p; p += (size_t)512 * 1024 * 2;   // Wq^T f16
    _Float16* yT   = (_Float16*)p; p += (size_t)256 * 8192 * 2;   // y^T f16
    _Float16* keys = (_Float16*)p; p += (size_t)8192 * 512 * 2;   // keys f16
    _Float16* qk   = (_Float16*)p; p += (size_t)4096 * 512 * 2;   // qk f16 (pre-scaled)
    _Float16* lg   = (_Float16*)p; p += (size_t)4096 * 8192 * 2;  // logits/p f16
    float*    part = (float*)p;    p += (size_t)4 * 4096 * 256 * 4; // PV split-K partials
    int*      flags = (int*)p;     p += 64 * 4;                   // PV tile counters

    // all preprocessing in one launch (also zeroes flags)
    k_preproc<<<15360, 256, 0, stream>>>(search_x, xh, query_x, qh,
                                         Wk, wkT, Wq, wqT, search_y, yT, flags);

    // merged projections: keys = x @ Wk (by<64); qk = (q @ Wq)/sqrt(512) (by>=64)
    k_gemm_nt<3><<<dim3(4, 96, 1), 256, 0, stream>>>(
        xh, wkT, keys, qh, wqT, qk, nullptr, nullptr,
        8192, 512, 1024, 1024, 1.0f, 0.04419417382415922f);

    // logits = qk @ keys^T  (scale folded into qk)
    k_gemm_nt<0><<<dim3(64, 32, 1), 256, 0, stream>>>(
        qk, keys, lg, nullptr, nullptr, nullptr, nullptr, nullptr,
        4096, 8192, 512, 512, 1.0f, 0.f);

    // masked softmax in-place
    k_softmax<<<4096, 256, 0, stream>>>(lg, mask);

    // out = p @ y  (M=4096,N=256,K=8192), split-K=4 with fused last-block reduce
    k_gemm_nt<1><<<dim3(2, 32, 4), 256, 0, stream>>>(
        lg, yT, part, nullptr, nullptr, nullptr, (float*)d_out, flags,
        4096, 256, 8192, 2048, 1.0f, 0.f);
}

// Round 9
// 351.547 us; speedup vs baseline: 1.1246x; 1.1246x over previous
//
#include <hip/hip_runtime.h>
#include <hip/hip_fp16.h>

typedef _Float16 half4v __attribute__((ext_vector_type(4)));
typedef _Float16 half8v __attribute__((ext_vector_type(8)));
typedef float floatx4 __attribute__((ext_vector_type(4)));

#define GLOBAL_AS __attribute__((address_space(1)))
#define LDS_AS __attribute__((address_space(3)))

// async 16B/lane global->LDS DMA; lds dest = wave-uniform base + lane*16
__device__ __forceinline__ void async_copy16(const _Float16* g, _Float16* l) {
    __builtin_amdgcn_global_load_lds((const GLOBAL_AS unsigned int*)g,
                                     (LDS_AS unsigned int*)l, 16, 0, 0);
}

// ---------------- fused preprocessing: converts + 3 transposes, one launch --------
__device__ __forceinline__ void transpose_tile(const float* __restrict__ in,
                                               _Float16* __restrict__ out,
                                               int R, int C, int bx, int by,
                                               float* tile /*[32][33]*/) {
    int tx = threadIdx.x & 31, ty = threadIdx.x >> 5;  // 32x8
    int bc = bx * 32, br = by * 32;
#pragma unroll
    for (int i = 0; i < 32; i += 8)
        tile[(ty + i) * 33 + tx] = in[(size_t)(br + ty + i) * C + bc + tx];
    __syncthreads();
#pragma unroll
    for (int i = 0; i < 32; i += 8)
        out[(size_t)(bc + ty + i) * R + br + tx] = (_Float16)tile[tx * 33 + ty + i];
}

__global__ __launch_bounds__(256) void k_preproc(const float* __restrict__ x,
                                                 _Float16* __restrict__ xh,
                                                 const float* __restrict__ q,
                                                 _Float16* __restrict__ qh,
                                                 const float* __restrict__ Wk,
                                                 _Float16* __restrict__ wkT,
                                                 const float* __restrict__ Wq,
                                                 _Float16* __restrict__ wqT,
                                                 const float* __restrict__ y,
                                                 _Float16* __restrict__ yT) {
    __shared__ float tile[32 * 33];
    const int b = blockIdx.x;
    if (b < 12288) {
        const int na = 8192 * 1024;
        int i = (b * 256 + threadIdx.x) * 4;
        const float* src;
        _Float16* dst;
        if (i < na) { src = x + i; dst = xh + i; }
        else        { src = q + (i - na); dst = qh + (i - na); }
        float4 v = *(const float4*)src;
        half4v h;
        h[0] = (_Float16)v.x; h[1] = (_Float16)v.y;
        h[2] = (_Float16)v.z; h[3] = (_Float16)v.w;
        *(half4v*)dst = h;
    } else if (b < 12800) {
        const int idx = b - 12288;
        transpose_tile(Wk, wkT, 1024, 512, idx & 15, idx >> 4, tile);
    } else if (b < 13312) {
        const int idx = b - 12800;
        transpose_tile(Wq, wqT, 1024, 512, idx & 15, idx >> 4, tile);
    } else {
        const int idx = b - 13312;
        transpose_tile(y, yT, 8192, 256, idx & 7, idx >> 3, tile);
    }
}

// ---------------- NT GEMM (m97-structure): C = scale * A @ B^T ----------------
// 128x128 tile, BK=64, 4 waves, mfma_f32_16x16x32_f16, global_load_lds width=16,
// chunk-XOR swizzle (LDS slot (row,c) holds global chunk (row, c^(row&7)));
// bank-conflict-free (proven SQ_LDS_BANK_CONFLICT==0).
// OUT_MODE 0: f16 store (scaled).
// OUT_MODE 1: f32 partial store at C + blockIdx.z*M*N (split-K; reduced by k_reduce).
// OUT_MODE 3: merged projections -- blockIdx.y >= 64 switches to (A2,B2,C2,scale2).
// Closed directions (measured): mask-in-epilogue (+35/+18us r1/r4), f32 atomic
// epilogue (+25us r3), fused last-block reduce w/ device fences (+42us r8),
// 8-phase deep pipeline (+5us r7 -- L2-resident inputs don't reward depth).
template <int OUT_MODE>
__global__ __launch_bounds__(256) void k_gemm_nt(const _Float16* __restrict__ A,
                                                 const _Float16* __restrict__ B,
                                                 void* __restrict__ C,
                                                 const _Float16* __restrict__ A2,
                                                 const _Float16* __restrict__ B2,
                                                 void* __restrict__ C2,
                                                 int M, int N, int K, int kChunk,
                                                 float scale, float scale2) {
    __shared__ __align__(16) _Float16 As[128 * 64];
    __shared__ __align__(16) _Float16 Bs[128 * 64];
    const int tid  = threadIdx.x;
    const int lane = tid & 63;
    const int wave = tid >> 6;
    const int wm   = (wave >> 1) * 64;
    const int wn   = (wave & 1) * 64;
    const int quad = lane >> 4;
    const int lr   = lane & 15;

    int by = blockIdx.y;
    if (OUT_MODE == 3 && by >= 64) {
        by -= 64;
        A = A2; B = B2; C = C2; scale = scale2;
    }
    const long m0 = (long)by * 128;
    const long n0 = (long)blockIdx.x * 128;
    const int kBegin = blockIdx.z * kChunk;
    const int kEnd   = kBegin + kChunk;

    floatx4 acc[4][4] = {};

    const int rl = lane >> 3;
    const int gc = (lane & 7) ^ rl;
    const long arow = m0 + wave * 32 + rl;
    const long brow = n0 + wave * 32 + rl;

    for (int kt = kBegin; kt < kEnd; kt += 64) {
        const _Float16* Ap = A + arow * (long)K + kt + gc * 8;
        const _Float16* Bp = B + brow * (long)K + kt + gc * 8;
        _Float16* Al = &As[(wave * 32) * 64];
        _Float16* Bl = &Bs[(wave * 32) * 64];
#pragma unroll
        for (int i = 0; i < 4; ++i) {
            async_copy16(Ap + (long)(i * 8) * K, Al + i * 8 * 64);
            async_copy16(Bp + (long)(i * 8) * K, Bl + i * 8 * 64);
        }
        __syncthreads();

#pragma unroll
        for (int kk = 0; kk < 64; kk += 32) {
            half8v af[4], bf[4];
            const int cg = (kk >> 3) + quad;
            const int sl = (cg ^ (lr & 7)) * 8;
#pragma unroll
            for (int i = 0; i < 4; ++i)
                af[i] = *(const half8v*)&As[(wm + i * 16 + lr) * 64 + sl];
#pragma unroll
            for (int j = 0; j < 4; ++j)
                bf[j] = *(const half8v*)&Bs[(wn + j * 16 + lr) * 64 + sl];
#pragma unroll
            for (int i = 0; i < 4; ++i)
#pragma unroll
                for (int j = 0; j < 4; ++j)
                    acc[i][j] = __builtin_amdgcn_mfma_f32_16x16x32_f16(af[i], bf[j], acc[i][j], 0, 0, 0);
        }
        __syncthreads();
    }

    // epilogue: C/D layout col = lane&15, row = quad*4 + reg  [m89/m91]
#pragma unroll
    for (int i = 0; i < 4; ++i) {
        long rbase = m0 + wm + i * 16 + quad * 4;
#pragma unroll
        for (int j = 0; j < 4; ++j) {
            long col = n0 + wn + j * 16 + lr;
#pragma unroll
            for (int r = 0; r < 4; ++r) {
                float val = acc[i][j][r] * scale;
                if (OUT_MODE == 1)
                    ((float*)C)[(size_t)blockIdx.z * M * N + (rbase + r) * (long)N + col] = val;
                else
                    ((_Float16*)C)[(rbase + r) * (long)N + col] = (_Float16)val;
            }
        }
    }
}

// ---------------- sum Z fp32 partials [Z][n] -> out[n] ----------------
template <int Z>
__global__ __launch_bounds__(256) void k_reduce(const float* __restrict__ part,
                                                float* __restrict__ out, int n) {
    int i = (blockIdx.x * 256 + threadIdx.x) * 4;
    if (i >= n) return;
    float4 s = *(const float4*)(part + i);
#pragma unroll
    for (int z = 1; z < Z; ++z) {
        float4 v = *(const float4*)(part + (size_t)z * n + i);
        s.x += v.x; s.y += v.y; s.z += v.z; s.w += v.w;
    }
    *(float4*)(out + i) = s;
}

// ---------------- masked softmax, in-place on f16 logits [4096][8192] ----------------
// Coalesced int4 mask + half4 logit loads; moves 268 MB (mask 134 + logits
// r67+w67) at its HBM roofline (~45 us). Mask fusion elsewhere: closed (r1/r4).
__global__ __launch_bounds__(256) void k_softmax(_Float16* __restrict__ logits,
                                                 const int* __restrict__ mask) {
    const int q   = blockIdx.x;
    const int tid = threadIdx.x;
    _Float16* row   = logits + (size_t)q * 8192;
    const int* mrow = mask + (size_t)q * 8192;

    float v[32];
    unsigned mb = 0;
    float lmax = -3.0e38f;
#pragma unroll
    for (int i = 0; i < 8; ++i) {
        int base = i * 1024 + tid * 4;
        int4 mm  = *(const int4*)(mrow + base);
        half4v h = *(const half4v*)(row + base);
#pragma unroll
        for (int j = 0; j < 4; ++j) v[i * 4 + j] = (float)h[j];
        if (mm.x > 0) { mb |= 1u << (i * 4 + 0); lmax = fmaxf(lmax, v[i * 4 + 0]); }
        if (mm.y > 0) { mb |= 1u << (i * 4 + 1); lmax = fmaxf(lmax, v[i * 4 + 1]); }
        if (mm.z > 0) { mb |= 1u << (i * 4 + 2); lmax = fmaxf(lmax, v[i * 4 + 2]); }
        if (mm.w > 0) { mb |= 1u << (i * 4 + 3); lmax = fmaxf(lmax, v[i * 4 + 3]); }
    }
#pragma unroll
    for (int off = 32; off > 0; off >>= 1) lmax = fmaxf(lmax, __shfl_xor(lmax, off, 64));
    __shared__ float redmax[4], redsum[4];
    if ((tid & 63) == 0) redmax[tid >> 6] = lmax;
    __syncthreads();
    lmax = fmaxf(fmaxf(redmax[0], redmax[1]), fmaxf(redmax[2], redmax[3]));

    float lsum = 0.f;
#pragma unroll
    for (int i = 0; i < 32; ++i) {
        float e = ((mb >> i) & 1u) ? __expf(v[i] - lmax) : 0.f;
        v[i] = e;
        lsum += e;
    }
#pragma unroll
    for (int off = 32; off > 0; off >>= 1) lsum += __shfl_xor(lsum, off, 64);
    if ((tid & 63) == 0) redsum[tid >> 6] = lsum;
    __syncthreads();
    lsum = redsum[0] + redsum[1] + redsum[2] + redsum[3];
    float inv = lsum > 0.f ? 1.f / lsum : 0.f;

#pragma unroll
    for (int i = 0; i < 8; ++i) {
        int base = i * 1024 + tid * 4;
        half4v h;
#pragma unroll
        for (int j = 0; j < 4; ++j) h[j] = (_Float16)(v[i * 4 + j] * inv);
        *(half4v*)(row + base) = h;
    }
}

extern "C" void kernel_launch(void* const* d_in, const int* in_sizes, int n_in,
                              void* d_out, int out_size, void* d_ws, size_t ws_size,
                              hipStream_t stream) {
    const float* search_x = (const float*)d_in[0];  // [8192,1024]
    const float* search_y = (const float*)d_in[1];  // [8192,256]
    const float* query_x  = (const float*)d_in[2];  // [4096,1024]
    const int*   mask     = (const int*)d_in[3];    // [4096,8192]
    const float* Wk       = (const float*)d_in[4];  // [1024,512]
    const float* Wq       = (const float*)d_in[5];  // [1024,512]
    (void)in_sizes; (void)n_in; (void)ws_size; (void)out_size;

    char* p = (char*)d_ws;
    _Float16* xh   = (_Float16*)p; p += (size_t)8192 * 1024 * 2;  // x f16
    _Float16* qh   = (_Float16*)p; p += (size_t)4096 * 1024 * 2;  // q f16
    _Float16* wkT  = (_Float16*)p; p += (size_t)512 * 1024 * 2;   // Wk^T f16
    _Float16* wqT  = (_Float16*)p; p += (size_t)512 * 1024 * 2;   // Wq^T f16
    _Float16* yT   = (_Float16*)p; p += (size_t)256 * 8192 * 2;   // y^T f16
    _Float16* keys = (_Float16*)p; p += (size_t)8192 * 512 * 2;   // keys f16
    _Float16* qk   = (_Float16*)p; p += (size_t)4096 * 512 * 2;   // qk f16 (pre-scaled)
    _Float16* lg   = (_Float16*)p; p += (size_t)4096 * 8192 * 2;  // logits/p f16
    float*    part = (float*)p;    p += (size_t)4 * 4096 * 256 * 4; // PV split-K partials

    // all preprocessing in one launch
    k_preproc<<<15360, 256, 0, stream>>>(search_x, xh, query_x, qh,
                                         Wk, wkT, Wq, wqT, search_y, yT);

    // merged projections: keys = x @ Wk (by<64); qk = (q @ Wq)/sqrt(512) (by>=64)
    k_gemm_nt<3><<<dim3(4, 96, 1), 256, 0, stream>>>(
        xh, wkT, keys, qh, wqT, qk, 8192, 512, 1024, 1024,
        1.0f, 0.04419417382415922f);

    // logits = qk @ keys^T  (scale already folded into qk)
    k_gemm_nt<0><<<dim3(64, 32, 1), 256, 0, stream>>>(
        qk, keys, lg, nullptr, nullptr, nullptr, 4096, 8192, 512, 512, 1.0f, 0.f);

    // masked softmax in-place
    k_softmax<<<4096, 256, 0, stream>>>(lg, mask);

    // out = p @ y  (M=4096,N=256,K=8192), split-K=4 -> fp32 partials, reduce
    k_gemm_nt<1><<<dim3(2, 32, 4), 256, 0, stream>>>(
        lg, yT, part, nullptr, nullptr, nullptr, 4096, 256, 8192, 2048, 1.0f, 0.f);
    k_reduce<4><<<1024, 256, 0, stream>>>(part, (float*)d_out, 4096 * 256);
}